// Round 22
// baseline (93.081 us; speedup 1.0000x reference)
//
#include <hip/hip_runtime.h>
#include <hip/hip_bf16.h>

#define DEVI __device__ __forceinline__

constexpr int B_ = 32, CI = 128, CM = 256, H_ = 32, W_ = 32;
constexpr int S_ = 1024, NB = 100;
constexpr float LAMF = 0.7f, ILAMF = 0.3f, SCALEF = 3.0f;
// chunked channel-last activation layouts: [b][ch/8][pos][8ch]
constexpr size_t XSZ = (size_t)32 * 16 * 1156 * 8;   // per-ab xpad elems (34x34 pos)
constexpr size_t XBS = (size_t)16 * 1156 * 8;        // per-b stride
constexpr size_t CSZ = (size_t)32 * 32 * 324 * 8;    // per-ab cpad elems (18x18 pos)
constexpr size_t CBS = (size_t)32 * 324 * 8;
constexpr size_t MPK = (size_t)2 * 32 * 16 * 128;    // per-kind stride in mpart

typedef short bf8 __attribute__((ext_vector_type(8)));
typedef float f4 __attribute__((ext_vector_type(4)));
typedef float f16v __attribute__((ext_vector_type(16)));
typedef unsigned short u16;
typedef unsigned int u32;

struct alignas(8) us4 { u16 v[4]; };
struct alignas(16) us8 { u16 v[8]; };

// deconv tap order, parity-grouped: par0{0,2,6,8} par3{4} | par1{1,7} par2{3,5}
__device__ __constant__ int TAPD9c[9] = {0, 2, 6, 8, 1, 7, 3, 5, 4};

DEVI u16 f2bf(float f) {
    unsigned u = __builtin_bit_cast(unsigned, f);
    u += 0x7FFFu + ((u >> 16) & 1u);
    return (u16)(u >> 16);
}
DEVI float bf2f(u16 h) {
    unsigned u = ((unsigned)h) << 16;
    return __builtin_bit_cast(float, u);
}

DEVI void gll16(const void* g, void* l) {
    __builtin_amdgcn_global_load_lds(
        (const __attribute__((address_space(1))) u32*)g,
        (__attribute__((address_space(3))) u32*)l, 16, 0, 0);
}

DEVI float waveSum(float v) {
#pragma unroll
    for (int off = 32; off > 0; off >>= 1) v += __shfl_down(v, off, 64);
    return v;
}
DEVI float blockSum256(float v, float* lds4) {
    v = waveSum(v);
    int wid = threadIdx.x >> 6, lane = threadIdx.x & 63;
    __syncthreads();
    if (lane == 0) lds4[wid] = v;
    __syncthreads();
    return lds4[0] + lds4[1] + lds4[2] + lds4[3];
}
DEVI float blockMax256(float v, float* lds4) {
#pragma unroll
    for (int off = 32; off > 0; off >>= 1) v = fmaxf(v, __shfl_down(v, off, 64));
    int wid = threadIdx.x >> 6, lane = threadIdx.x & 63;
    __syncthreads();
    if (lane == 0) lds4[wid] = v;
    __syncthreads();
    return fmaxf(fmaxf(lds4[0], lds4[1]), fmaxf(lds4[2], lds4[3]));
}
DEVI float blockSum128(float v, float* lds2) {
    v = waveSum(v);
    int wid = threadIdx.x >> 6, lane = threadIdx.x & 63;
    __syncthreads();
    if (lane == 0) lds2[wid] = v;
    __syncthreads();
    return lds2[0] + lds2[1];
}

// ---- k_setup: prep_w(1152) | prox(50) | ring(64) | xpose(1024) fused ----
__global__ __launch_bounds__(256) void k_setup(const float* __restrict__ xa,
                                               const float* __restrict__ xb,
                                               const float* __restrict__ P,
                                               const float* __restrict__ We,
                                               const float* __restrict__ Wf,
                                               const float* __restrict__ Wd,
                                               u16* __restrict__ A1p,
                                               u16* __restrict__ A2p,
                                               u16* __restrict__ A3p,
                                               float* __restrict__ PnT,
                                               float* __restrict__ pn2,
                                               u16* __restrict__ xpad,
                                               u16* __restrict__ cpad,
                                               float* __restrict__ mpart) {
    __shared__ float ldsx[128][64];
    __shared__ float sred[256];
    __shared__ float sinv[64];
    int bid = blockIdx.x, t = threadIdx.x;
    if (bid < 1152) {
        int i = bid * 256 + t;  // 294912
        {
            int e = i & 7, s = (i >> 3) & 511, j = i >> 12;
            int Mt = j / 36, kc = j - Mt * 36;
            int tap = kc >> 2, cq = kc & 3;
            int q = s >> 7, m = s & 127;
            int oc = Mt * 128 + m, ch = cq * 32 + q * 8 + e;
            A1p[i] = f2bf(We[((size_t)oc * CI + ch) * 9 + tap]);
        }
        {
            int e = i & 7, s = (i >> 3) & 511, kc = i >> 12;
            int tapi = kc >> 3, cq = kc & 7;
            int q = s >> 7, m = s & 127;
            int ch = cq * 32 + q * 8 + e;
            A2p[i] = f2bf(Wf[((size_t)m * CM + ch) * 9 + tapi]);
            A3p[i] = f2bf(Wd[((size_t)m * CM + ch) * 9 + TAPD9c[tapi]]);
        }
    } else if (bid < 1202) {
        int k = 2 * (bid - 1152) + (t >> 7);
        int lane = t & 127;
        float v = P[k * CI + lane];
        float vv = waveSum(v * v);
        __syncthreads();
        if ((t & 63) == 0) sred[t >> 6] = vv;
        __syncthreads();
        int hb = (t >> 7) * 2;
        float ss = sred[hb] + sred[hb + 1];
        float sc = SCALEF / fmaxf(sqrtf(ss), 1e-12f);
        float pv = v * sc;
        PnT[lane * NB + k] = pv;
        float p2 = waveSum(pv * pv);
        __syncthreads();
        if ((t & 63) == 0) sred[t >> 6] = p2;
        __syncthreads();
        float s2 = sred[hb] + sred[hb + 1];
        if (lane == 0) pn2[k] = s2;
    } else if (bid < 1266) {
        int idx = bid - 1202;
        int b = idx & 31, ab = idx >> 5;
        u16* xp = xpad + (size_t)ab * XSZ + (size_t)b * XBS;
        u16* cp = cpad + (size_t)ab * CSZ + (size_t)b * CBS;
        us8 z = {};
        for (int i = t; i < 132 * 16; i += 256) {
            int cc = i / 132, rp = i - cc * 132;
            int pos;
            if (rp < 68) pos = (rp < 34) ? (32 * 34 + rp) : (33 * 34 + rp - 34);
            else { int r2 = rp - 68; pos = (r2 >> 1) * 34 + 32 + (r2 & 1); }
            *(us8*)(xp + ((size_t)cc * 1156 + pos) * 8) = z;
        }
        for (int i = t; i < 68 * 32; i += 256) {
            int cc = i / 68, rp = i - cc * 68;
            int pos;
            if (rp < 36) pos = (rp < 18) ? rp : (17 * 18 + rp - 18);
            else { int r2 = rp - 36; pos = (1 + (r2 >> 1)) * 18 + ((r2 & 1) ? 17 : 0); }
            *(us8*)(cp + ((size_t)cc * 324 + pos) * 8) = z;
        }
    } else {
        int idx = bid - 1266;      // 0..1023
        int b = idx & 31, yg = (idx >> 5) & 15, ab = idx >> 9;
        const float* x = (ab ? xb : xa) + (size_t)b * CI * S_ + yg * 64;
        int cf = t >> 4, p4 = (t & 15) * 4;
#pragma unroll
        for (int c0 = 0; c0 < 8; ++c0) {
            int c = c0 * 16 + cf;
            f4 v = *(const f4*)(x + (size_t)c * S_ + p4);
            *(f4*)&ldsx[c][p4] = v;
        }
        __syncthreads();
        int qc = t >> 6, p = t & 63;
        int y = yg * 2 + (p >> 5), xcol = p & 31;
        u16* ox = xpad + (size_t)ab * XSZ + (size_t)b * XBS;
        float ss = 0.f;
#pragma unroll
        for (int c8 = 0; c8 < 4; ++c8) {
            int cb = qc * 32 + c8 * 8;
            int cc = cb >> 3;
            us8 pk;
#pragma unroll
            for (int j = 0; j < 8; ++j) {
                float v = ldsx[cb + j][p];
                ss = fmaf(v, v, ss);
                pk.v[j] = f2bf(v);
            }
            *(us8*)(ox + ((size_t)cc * 1156 + y * 34 + xcol) * 8) = pk;
        }
        sred[t] = ss;
        __syncthreads();
        if (t < 64) {
            float s = sred[t] + sred[t + 64] + sred[t + 128] + sred[t + 192];
            sinv[t] = 1.f / fmaxf(sqrtf(s), 1e-12f);
        }
        __syncthreads();
        int c = t >> 1, h = t & 1;
        float sx = 0.f, sf = 0.f;
        for (int i = 0; i < 32; ++i) {
            int p2 = h * 32 + ((i + c) & 31);
            float v = ldsx[c][p2];
            sx += v;
            sf = fmaf(v, sinv[p2], sf);
        }
        sx += __shfl_xor(sx, 1, 64);
        sf += __shfl_xor(sf, 1, 64);
        if (!(t & 1)) {
            size_t base = ((size_t)(ab * 32 + b) * 16 + yg) * 128 + c;
            mpart[base] = sx * (1.f / 1024.f);
            mpart[MPK + base] = sf * (1.f / 1024.f);
        }
    }
}

// ---- conv1: K-64 steps (18), T4 counted-vmcnt (unchanged from R18/R20) ----
__global__ __launch_bounds__(256, 2) void k_conv1g(const u16* __restrict__ XC,
                                                   const u16* __restrict__ A1p,
                                                   u16* __restrict__ CC) {
    __shared__ u16 sA[2][8192];
    __shared__ u16 sB[2][4096];
    int t = threadIdx.x, l = t & 63, l15 = l & 15, lq = l >> 4, w = t >> 6;
    int wm = w & 1, wn = w >> 1;
    int Nt = blockIdx.x, b = blockIdx.y;
    int ab = blockIdx.z & 1, Mt = blockIdx.z >> 1;
    const u16* xc = XC + (size_t)ab * XSZ + (size_t)b * XBS;
    const u16* Ag = A1p + (size_t)Mt * (36 * 4096);
    int bpos0 = (8 * Nt + 2 * (l >> 4)) * 34 + 2 * (l & 15);
    const int po1[9] = {0, 1, 2, 34, 35, 36, 68, 69, 70};

    auto stageA = [&](int buf, int kcA) {
        const u16* ga = Ag + (size_t)kcA * 4096 + t * 8;
        u16* da = &sA[buf][w * 512];
#pragma unroll
        for (int i = 0; i < 4; ++i) gll16(ga + i * 2048, da + i * 2048);
    };
    auto stageB = [&](int buf, int po, int s) {
#pragma unroll
        for (int i = 0; i < 2; ++i) {
            int ks = i * 4 + w;
            gll16(xc + ((size_t)(s * 8 + ks) * 1156 + bpos0 + po) * 8,
                  &sB[buf][(size_t)ks * 512]);
        }
    };

    f4 acc[4][2] = {};
    stageA(0, 0);
    stageB(0, 0, 0);
    int cur = 0;
#pragma unroll
    for (int ti = 0; ti < 9; ++ti) {
        const int po = po1[ti];
        const int poN = (ti < 8) ? po1[ti + 1] : 0;
#pragma unroll 1
        for (int s = 0; s < 2; ++s) {
            __builtin_amdgcn_s_barrier();
            bool last = (ti == 8) && (s == 1);
            if (!last) {
                int tin = (s < 1) ? ti : ti + 1;
                int sn = (s < 1) ? 1 : 0;
                stageA(cur ^ 1, tin * 4 + sn * 2);
                stageB(cur ^ 1, (s < 1) ? po : poN, sn);
                asm volatile("s_waitcnt vmcnt(6)" ::: "memory");
            } else {
                asm volatile("s_waitcnt vmcnt(0)" ::: "memory");
            }
            __builtin_amdgcn_s_barrier();
            const u16* As = sA[cur];
            const u16* Bs = sB[cur];
#pragma unroll
            for (int kc2 = 0; kc2 < 2; ++kc2) {
                bf8 af[4], bv[2];
#pragma unroll
                for (int mf = 0; mf < 4; ++mf)
                    af[mf] = *(const bf8*)(As + ((kc2 * 4 + lq) * 128 + wm * 64 + mf * 16 + l15) * 8);
#pragma unroll
                for (int nf = 0; nf < 2; ++nf)
                    bv[nf] = *(const bf8*)(Bs + ((kc2 * 4 + lq) * 64 + wn * 32 + nf * 16 + l15) * 8);
#pragma unroll
                for (int mf = 0; mf < 4; ++mf)
#pragma unroll
                    for (int nf = 0; nf < 2; ++nf)
                        acc[mf][nf] = __builtin_amdgcn_mfma_f32_16x16x32_bf16(af[mf], bv[nf], acc[mf][nf], 0, 0, 0);
            }
            cur ^= 1;
        }
    }
    u16* cb = CC + (size_t)ab * CSZ + (size_t)b * CBS;
#pragma unroll
    for (int mf = 0; mf < 4; ++mf) {
        int mc = Mt * 128 + wm * 64 + mf * 16 + lq * 4;
#pragma unroll
        for (int nf = 0; nf < 2; ++nf) {
            int nl = wn * 32 + nf * 16 + l15;
            int oh = Nt * 4 + (nl >> 4), ow = nl & 15;
            int posO = (1 + oh) * 18 + 1 + ow;
            us4 pk;
#pragma unroll
            for (int r = 0; r < 4; ++r) pk.v[r] = f2bf(fmaxf(acc[mf][nf][r], 0.f));
            *(us4*)(cb + ((size_t)(mc >> 3) * 324 + posO) * 8 + (mc & 7)) = pk;
        }
    }
}

// ---- k_cde12: A operands global->register; LDS = resident B-slab only ----
// Barrier-free K-steps (TLP hides A L2 latency); __syncthreads only around
// slab restage. Per step: 8 coalesced global b128 A-loads + 8 ds_read_b128
// + 16 mfma_32x32x16. grid (2 Nt, 32 b, 8: unit*2+ab)

#define KSTEP(ACC, KYV, KXV, KCC)                                                   \
    {                                                                               \
        _Pragma("unroll") for (int kc2 = 0; kc2 < 2; ++kc2) {                       \
            _Pragma("unroll") for (int j = 0; j < 2; ++j) {                         \
                const u16* ap = Ag + (size_t)((KCC) + kc2) * 4096 + j * 2048 + aBase; \
                bf8 a0 = *(const bf8*)(ap);                                         \
                bf8 a1 = *(const bf8*)(ap + 256);                                   \
                const u16* bp = sS + (kc2 * 720 + j * 360) * 8 + bBase;             \
                bf8 b0 = *(const bf8*)(bp + (((KYV)) * 18 + (KXV)) * 8);            \
                bf8 b1 = *(const bf8*)(bp + (((KYV) + 2) * 18 + (KXV)) * 8);        \
                ACC[0][0] = __builtin_amdgcn_mfma_f32_32x32x16_bf16(a0, b0, ACC[0][0], 0, 0, 0); \
                ACC[0][1] = __builtin_amdgcn_mfma_f32_32x32x16_bf16(a0, b1, ACC[0][1], 0, 0, 0); \
                ACC[1][0] = __builtin_amdgcn_mfma_f32_32x32x16_bf16(a1, b0, ACC[1][0], 0, 0, 0); \
                ACC[1][1] = __builtin_amdgcn_mfma_f32_32x32x16_bf16(a1, b1, ACC[1][1], 0, 0, 0); \
            }                                                                       \
        }                                                                           \
    }

#define FLUSH(ACC, PY, PX)                                                          \
    _Pragma("unroll") for (int mf = 0; mf < 2; ++mf) {                              \
        _Pragma("unroll") for (int nf = 0; nf < 2; ++nf) {                          \
            int n = wn * 64 + nf * 32 + l31;                                        \
            int oh = 8 * Nt + (n >> 4), ow = n & 15;                                \
            int Y = 2 * oh + (PY), X = 2 * ow + (PX);                               \
            _Pragma("unroll") for (int rg = 0; rg < 4; ++rg) {                      \
                int mc = wm * 64 + mf * 32 + 8 * rg + 4 * lh;                       \
                us4 xv = *(const us4*)(xq + (size_t)(mc >> 3) * 1156 * 8 +          \
                                       (size_t)(Y * 34 + X) * 8 + (mc & 7));        \
                _Pragma("unroll") for (int r = 0; r < 4; ++r) {                     \
                    float d = ACC[mf][nf][rg * 4 + r] - bf2f(xv.v[r]);              \
                    ss = fmaf(d, d, ss);                                            \
                }                                                                   \
            }                                                                       \
        }                                                                           \
    }

__global__ __launch_bounds__(256, 2) void k_cde12(const u16* __restrict__ CC,
                                                  const u16* __restrict__ A2p,
                                                  const u16* __restrict__ A3p,
                                                  const u16* __restrict__ XC,
                                                  u16* __restrict__ pc0,
                                                  u16* __restrict__ pc1,
                                                  float* __restrict__ prpart) {
    __shared__ u16 sS[11520];     // [ccL8][pos 10x18][8e] = 22.5KB (only LDS)
    __shared__ float lds4[4];
    int t = threadIdx.x, l = t & 63, l31 = l & 31, lh = l >> 5, w = t >> 6;
    int wm = w & 1, wn = w >> 1;
    int Nt = blockIdx.x, b = blockIdx.y;
    int ab = blockIdx.z & 1, unit = blockIdx.z >> 1;
    const u16* cbb = CC + (size_t)ab * CSZ + (size_t)b * CBS;
    const u16* xq = XC + (size_t)ab * XSZ + (size_t)b * XBS;
    const u16* Ag = (unit < 2) ? A2p : A3p;
    int r0 = 8 * Nt;
    int aBase = (lh * 128 + wm * 64 + l31) * 8;
    int bBase = (lh * 180 + (wn * 4 + (l31 >> 4)) * 18 + (l31 & 15)) * 8;

    auto stage_slab = [&](int seg) {
        if (t < 180) {
            int cc0 = (seg >> 1) * 16 + (seg & 1) * 8;
#pragma unroll 1
            for (int ccL = 0; ccL < 8; ++ccL) {
                us8 v = *(const us8*)(cbb + ((size_t)(cc0 + ccL) * 324 + r0 * 18 + t) * 8);
                *(us8*)(sS + ((size_t)ccL * 180 + t) * 8) = v;
            }
        }
    };

    float ss = 0.f;
    if (unit < 2) {
        f16v acc[2][2] = {};
        int segBase = unit * 2;
#pragma unroll
        for (int sl = 0; sl < 2; ++sl) {
            int seg = segBase + sl;
            if (sl) __syncthreads();     // readers done with old slab
            stage_slab(seg);
            __syncthreads();             // slab published
#pragma unroll 1
            for (int tap = 0; tap < 9; ++tap) {
                int ky = tap / 3, kx = tap - ky * 3;
                int kc = tap * 8 + (seg >> 1) * 4 + (seg & 1) * 2;
                KSTEP(acc, ky, kx, kc);
            }
        }
        u16* pw = (unit == 0 ? pc0 : pc1) + (size_t)(ab * 32 + b) * 32768;
#pragma unroll
        for (int mf = 0; mf < 2; ++mf)
#pragma unroll
            for (int nf = 0; nf < 2; ++nf) {
                int pos = 128 * Nt + wn * 64 + nf * 32 + l31;
                u16* row = pw + (size_t)pos * 128 + wm * 64 + mf * 32 + 4 * lh;
#pragma unroll
                for (int g = 0; g < 4; ++g) {
                    us4 pk;
#pragma unroll
                    for (int r = 0; r < 4; ++r) pk.v[r] = f2bf(acc[mf][nf][4 * g + r]);
                    *(us4*)(row + 8 * g) = pk;
                }
            }
    } else if (unit == 2) {
        f16v accP[2][2] = {}, accQ[2][2] = {};
#pragma unroll
        for (int seg = 0; seg < 4; ++seg) {
            if (seg) __syncthreads();
            stage_slab(seg);
            __syncthreads();
#pragma unroll 1
            for (int r = 0; r < 5; ++r) {
                int tapi = (r < 4) ? r : 8;
                int kc = tapi * 8 + (seg >> 1) * 4 + (seg & 1) * 2;
                if (r < 4) {
                    int dy = r >> 1, dx = r & 1;
                    KSTEP(accP, dy, dx, kc);
                } else {
                    KSTEP(accQ, 1, 1, kc);
                }
            }
        }
        FLUSH(accP, 0, 0);
        FLUSH(accQ, 1, 1);
        ss = blockSum256(ss, lds4);
        if (t == 0) prpart[ab * 128 + Nt * 32 + b] = ss;
    } else {
        f16v accP[2][2] = {}, accQ[2][2] = {};
#pragma unroll
        for (int seg = 0; seg < 4; ++seg) {
            if (seg) __syncthreads();
            stage_slab(seg);
            __syncthreads();
#pragma unroll 1
            for (int r = 0; r < 4; ++r) {
                int kc = (4 + r) * 8 + (seg >> 1) * 4 + (seg & 1) * 2;
                if (r < 2) {
                    KSTEP(accP, r, 1, kc);
                } else {
                    KSTEP(accQ, 1, r - 2, kc);
                }
            }
        }
        FLUSH(accP, 0, 1);
        FLUSH(accQ, 1, 0);
        ss = blockSum256(ss, lds4);
        if (t == 0) prpart[ab * 128 + 64 + Nt * 32 + b] = ss;
    }
}

#undef KSTEP
#undef FLUSH

// ---- metric: 256 threads/block; conv2-reduce split across half-blocks ----
__global__ __launch_bounds__(256) void k_metric(const u16* __restrict__ pc0,
                                                const u16* __restrict__ pc1,
                                                const float* __restrict__ mpart,
                                                const float* __restrict__ PnT,
                                                const float* __restrict__ pn2,
                                                const int* __restrict__ la,
                                                const int* __restrict__ lb,
                                                float* __restrict__ mo) {
    __shared__ float lds4[4];
    __shared__ float sred[256];
    __shared__ float xs[128];
    int blk = blockIdx.x;
    int t = threadIdx.x;
    int b = blk & 31;
    int oc = t & 127, th = t >> 7;   // th = pos-half
    float xv = 0.f;
    if (blk < 64) {
        int ab = blk >> 5;
        const u16* p0 = pc0 + (size_t)(ab * 32 + b) * 32768 + (size_t)th * 128 * 128;
        const u16* p1 = pc1 + (size_t)(ab * 32 + b) * 32768 + (size_t)th * 128 * 128;
        float s = 0.f;
#pragma unroll 4
        for (int pos = 0; pos < 128; ++pos)
            s += fmaxf(bf2f(p0[pos * 128 + oc]) + bf2f(p1[pos * 128 + oc]), 0.f);
        sred[t] = s;
        __syncthreads();
        if (t < 128) xv = (sred[t] + sred[t + 128]) * (1.f / 256.f);
    } else {
        if (t < 128) {
            int abx = (blk < 96) ? 0 : 1;
            int abf = 1 - abx;
            const float* mx = mpart + ((size_t)(abx * 32 + b) * 16) * 128 + t;
            const float* mf = mpart + MPK + ((size_t)(abf * 32 + b) * 16) * 128 + t;
            float s = 0.f;
#pragma unroll
            for (int yg = 0; yg < 16; ++yg)
                s += LAMF * mx[yg * 128] + ILAMF * mf[yg * 128];
            xv = s;
        }
    }
    float ssq = blockSum256(xv * xv, lds4);
    float sc = SCALEF / fmaxf(sqrtf(ssq), 1e-12f);
    float xn = xv * sc;
    if (t < 128) xs[t] = xn;
    float xn2 = blockSum256(xn * xn, lds4);   // has syncthreads -> xs visible
    bool active = (t < NB);
    float Dk = 1e30f;
    if (active) {
        float dot = 0.f;
#pragma unroll 8
        for (int e = 0; e < CI; ++e) dot = fmaf(xs[e], PnT[e * NB + t], dot);
        Dk = xn2 + pn2[t] - 2.f * dot;
    }
    float z = active ? -Dk : -1e30f;
    float m = blockMax256(z, lds4);
    float e = active ? expf(z - m) : 0.f;
    float se = blockSum256(e, lds4);
    float lse = m + logf(se);
    if (t == 0) mo[blk * 3 + 0] = lse;
    int A = la[b], Bb = lb[b];
    if (t == A) mo[blk * 3 + 1] = Dk;
    if (t == Bb) mo[blk * 3 + 2] = Dk;
}

__global__ __launch_bounds__(128) void k_final(const float* __restrict__ prpart,
                                               const float* __restrict__ mo,
                                               float* __restrict__ out) {
    __shared__ float lds2[2];
    __shared__ float mla[4], mlb[4];
    int t = threadIdx.x;
    float sa = blockSum128(prpart[t], lds2);
    float sb = blockSum128(prpart[128 + t], lds2);
    const float* m = mo + t * 3;
    float ula = m[0] + m[1];
    float ulb = m[0] + m[2];
#pragma unroll
    for (int off = 16; off > 0; off >>= 1) {
        ula += __shfl_down(ula, off, 32);
        ulb += __shfl_down(ulb, off, 32);
    }
    if ((t & 31) == 0) { mla[t >> 5] = ula * (1.f / 32.f); mlb[t >> 5] = ulb * (1.f / 32.f); }
    __syncthreads();
    if (t == 0) {
        float lxa = sa * (1.f / 4194304.f);
        float lxb = sb * (1.f / 4194304.f);
        float lca = mla[0];
        float lcb = mlb[1];
        float lcma = LAMF * mla[2] + ILAMF * mlb[2];
        float lcmb = LAMF * mlb[3] + ILAMF * mla[3];
        out[0] = lxa + lxb + lca + lcb + lcma + lcmb;
        out[1] = lxa; out[2] = lxb; out[3] = lca; out[4] = lcb; out[5] = lcma; out[6] = lcmb;
    }
}

extern "C" void kernel_launch(void* const* d_in, const int* in_sizes, int n_in,
                              void* d_out, int out_size, void* d_ws, size_t ws_size,
                              hipStream_t stream) {
    const float* xa = (const float*)d_in[0];
    const float* xb = (const float*)d_in[1];
    const int* la = (const int*)d_in[2];
    const int* lb = (const int*)d_in[3];
    const float* P = (const float*)d_in[4];
    const float* We = (const float*)d_in[5];
    const float* Wf = (const float*)d_in[6];
    const float* Wd = (const float*)d_in[7];

    char* w = (char*)d_ws;
    const size_t XPAD_B = XSZ * 2 * sizeof(u16);
    const size_t CPAD_B = CSZ * 2 * sizeof(u16);
    const size_t AW_B = (size_t)294912 * 2;
    u16* xpad = (u16*)w;                 w += XPAD_B;
    u16* cpad = (u16*)w;                 w += CPAD_B;
    u16* A1p = (u16*)w;                  w += AW_B;
    u16* A2p = (u16*)w;                  w += AW_B;
    u16* A3p = (u16*)w;                  w += AW_B;
    float* PnT = (float*)w;              w += 12800 * 4;
    float* pn2 = (float*)w;              w += 128 * 4;
    float* mpart = (float*)w;            w += MPK * 2 * 4;
    float* prpart = (float*)w;           w += 256 * 4;
    float* mo = (float*)w;               w += 384 * 4;
    u16* pc0 = (u16*)w;                  w += (size_t)2 * 32 * 32768 * 2;  // 4.2MB
    u16* pc1 = (u16*)w;                  w += (size_t)2 * 32 * 32768 * 2;  // 4.2MB
    float* out = (float*)d_out;

    k_setup<<<2290, 256, 0, stream>>>(xa, xb, P, We, Wf, Wd, A1p, A2p, A3p,
                                      PnT, pn2, xpad, cpad, mpart);
    k_conv1g<<<dim3(4, 32, 4), 256, 0, stream>>>(xpad, A1p, cpad);
    k_cde12<<<dim3(2, 32, 8), 256, 0, stream>>>(cpad, A2p, A3p, xpad, pc0, pc1, prpart);
    k_metric<<<128, 256, 0, stream>>>(pc0, pc1, mpart, PnT, pn2, la, lb, mo);
    k_final<<<1, 128, 0, stream>>>(prpart, mo, out);
}

// Round 23
// 83.717 us; speedup vs baseline: 1.1118x; 1.1118x over previous
//
#include <hip/hip_runtime.h>
#include <hip/hip_bf16.h>

#define DEVI __device__ __forceinline__

constexpr int B_ = 32, CI = 128, CM = 256, H_ = 32, W_ = 32;
constexpr int S_ = 1024, NB = 100;
constexpr float LAMF = 0.7f, ILAMF = 0.3f, SCALEF = 3.0f;
// chunked channel-last activation layouts: [b][ch/8][pos][8ch]
constexpr size_t XSZ = (size_t)32 * 16 * 1156 * 8;   // per-ab xpad elems (34x34 pos)
constexpr size_t XBS = (size_t)16 * 1156 * 8;        // per-b stride
constexpr size_t CSZ = (size_t)32 * 32 * 324 * 8;    // per-ab cpad elems (18x18 pos)
constexpr size_t CBS = (size_t)32 * 324 * 8;
constexpr size_t MPK = (size_t)2 * 32 * 16 * 128;    // per-kind stride in mpart

typedef short bf8 __attribute__((ext_vector_type(8)));
typedef float f4 __attribute__((ext_vector_type(4)));
typedef float f16v __attribute__((ext_vector_type(16)));
typedef unsigned short u16;
typedef unsigned int u32;

struct alignas(8) us4 { u16 v[4]; };
struct alignas(16) us8 { u16 v[8]; };

// deconv tap order, parity-grouped: par0{0,2,6,8} par3{4} | par1{1,7} par2{3,5}
__device__ __constant__ int TAPD9c[9] = {0, 2, 6, 8, 1, 7, 3, 5, 4};

DEVI u16 f2bf(float f) {
    unsigned u = __builtin_bit_cast(unsigned, f);
    u += 0x7FFFu + ((u >> 16) & 1u);
    return (u16)(u >> 16);
}
DEVI float bf2f(u16 h) {
    unsigned u = ((unsigned)h) << 16;
    return __builtin_bit_cast(float, u);
}

DEVI void gll16(const void* g, void* l) {
    __builtin_amdgcn_global_load_lds(
        (const __attribute__((address_space(1))) u32*)g,
        (__attribute__((address_space(3))) u32*)l, 16, 0, 0);
}

DEVI float waveSum(float v) {
#pragma unroll
    for (int off = 32; off > 0; off >>= 1) v += __shfl_down(v, off, 64);
    return v;
}
DEVI float blockSum256(float v, float* lds4) {
    v = waveSum(v);
    int wid = threadIdx.x >> 6, lane = threadIdx.x & 63;
    __syncthreads();
    if (lane == 0) lds4[wid] = v;
    __syncthreads();
    return lds4[0] + lds4[1] + lds4[2] + lds4[3];
}
DEVI float blockMax256(float v, float* lds4) {
#pragma unroll
    for (int off = 32; off > 0; off >>= 1) v = fmaxf(v, __shfl_down(v, off, 64));
    int wid = threadIdx.x >> 6, lane = threadIdx.x & 63;
    __syncthreads();
    if (lane == 0) lds4[wid] = v;
    __syncthreads();
    return fmaxf(fmaxf(lds4[0], lds4[1]), fmaxf(lds4[2], lds4[3]));
}
DEVI float blockSum128(float v, float* lds2) {
    v = waveSum(v);
    int wid = threadIdx.x >> 6, lane = threadIdx.x & 63;
    __syncthreads();
    if (lane == 0) lds2[wid] = v;
    __syncthreads();
    return lds2[0] + lds2[1];
}

// ---- k_setup: prep_w(1152) | prox(50) | ring(64) | xpose(1024) fused ----
__global__ __launch_bounds__(256) void k_setup(const float* __restrict__ xa,
                                               const float* __restrict__ xb,
                                               const float* __restrict__ P,
                                               const float* __restrict__ We,
                                               const float* __restrict__ Wf,
                                               const float* __restrict__ Wd,
                                               u16* __restrict__ A1p,
                                               u16* __restrict__ A2p,
                                               u16* __restrict__ A3p,
                                               float* __restrict__ PnT,
                                               float* __restrict__ pn2,
                                               u16* __restrict__ xpad,
                                               u16* __restrict__ cpad,
                                               float* __restrict__ mpart) {
    __shared__ float ldsx[128][64];
    __shared__ float sred[256];
    __shared__ float sinv[64];
    int bid = blockIdx.x, t = threadIdx.x;
    if (bid < 1152) {
        int i = bid * 256 + t;  // 294912
        {
            int e = i & 7, s = (i >> 3) & 511, j = i >> 12;
            int Mt = j / 36, kc = j - Mt * 36;
            int tap = kc >> 2, cq = kc & 3;
            int q = s >> 7, m = s & 127;
            int oc = Mt * 128 + m, ch = cq * 32 + q * 8 + e;
            A1p[i] = f2bf(We[((size_t)oc * CI + ch) * 9 + tap]);
        }
        {
            int e = i & 7, s = (i >> 3) & 511, kc = i >> 12;
            int tapi = kc >> 3, cq = kc & 7;
            int q = s >> 7, m = s & 127;
            int ch = cq * 32 + q * 8 + e;
            A2p[i] = f2bf(Wf[((size_t)m * CM + ch) * 9 + tapi]);
            A3p[i] = f2bf(Wd[((size_t)m * CM + ch) * 9 + TAPD9c[tapi]]);
        }
    } else if (bid < 1202) {
        int k = 2 * (bid - 1152) + (t >> 7);
        int lane = t & 127;
        float v = P[k * CI + lane];
        float vv = waveSum(v * v);
        __syncthreads();
        if ((t & 63) == 0) sred[t >> 6] = vv;
        __syncthreads();
        int hb = (t >> 7) * 2;
        float ss = sred[hb] + sred[hb + 1];
        float sc = SCALEF / fmaxf(sqrtf(ss), 1e-12f);
        float pv = v * sc;
        PnT[lane * NB + k] = pv;
        float p2 = waveSum(pv * pv);
        __syncthreads();
        if ((t & 63) == 0) sred[t >> 6] = p2;
        __syncthreads();
        float s2 = sred[hb] + sred[hb + 1];
        if (lane == 0) pn2[k] = s2;
    } else if (bid < 1266) {
        int idx = bid - 1202;
        int b = idx & 31, ab = idx >> 5;
        u16* xp = xpad + (size_t)ab * XSZ + (size_t)b * XBS;
        u16* cp = cpad + (size_t)ab * CSZ + (size_t)b * CBS;
        us8 z = {};
        for (int i = t; i < 132 * 16; i += 256) {
            int cc = i / 132, rp = i - cc * 132;
            int pos;
            if (rp < 68) pos = (rp < 34) ? (32 * 34 + rp) : (33 * 34 + rp - 34);
            else { int r2 = rp - 68; pos = (r2 >> 1) * 34 + 32 + (r2 & 1); }
            *(us8*)(xp + ((size_t)cc * 1156 + pos) * 8) = z;
        }
        for (int i = t; i < 68 * 32; i += 256) {
            int cc = i / 68, rp = i - cc * 68;
            int pos;
            if (rp < 36) pos = (rp < 18) ? rp : (17 * 18 + rp - 18);
            else { int r2 = rp - 36; pos = (1 + (r2 >> 1)) * 18 + ((r2 & 1) ? 17 : 0); }
            *(us8*)(cp + ((size_t)cc * 324 + pos) * 8) = z;
        }
    } else {
        int idx = bid - 1266;      // 0..1023
        int b = idx & 31, yg = (idx >> 5) & 15, ab = idx >> 9;
        const float* x = (ab ? xb : xa) + (size_t)b * CI * S_ + yg * 64;
        int cf = t >> 4, p4 = (t & 15) * 4;
#pragma unroll
        for (int c0 = 0; c0 < 8; ++c0) {
            int c = c0 * 16 + cf;
            f4 v = *(const f4*)(x + (size_t)c * S_ + p4);
            *(f4*)&ldsx[c][p4] = v;
        }
        __syncthreads();
        int qc = t >> 6, p = t & 63;
        int y = yg * 2 + (p >> 5), xcol = p & 31;
        u16* ox = xpad + (size_t)ab * XSZ + (size_t)b * XBS;
        float ss = 0.f;
#pragma unroll
        for (int c8 = 0; c8 < 4; ++c8) {
            int cb = qc * 32 + c8 * 8;
            int cc = cb >> 3;
            us8 pk;
#pragma unroll
            for (int j = 0; j < 8; ++j) {
                float v = ldsx[cb + j][p];
                ss = fmaf(v, v, ss);
                pk.v[j] = f2bf(v);
            }
            *(us8*)(ox + ((size_t)cc * 1156 + y * 34 + xcol) * 8) = pk;
        }
        sred[t] = ss;
        __syncthreads();
        if (t < 64) {
            float s = sred[t] + sred[t + 64] + sred[t + 128] + sred[t + 192];
            sinv[t] = 1.f / fmaxf(sqrtf(s), 1e-12f);
        }
        __syncthreads();
        int c = t >> 1, h = t & 1;
        float sx = 0.f, sf = 0.f;
        for (int i = 0; i < 32; ++i) {
            int p2 = h * 32 + ((i + c) & 31);
            float v = ldsx[c][p2];
            sx += v;
            sf = fmaf(v, sinv[p2], sf);
        }
        sx += __shfl_xor(sx, 1, 64);
        sf += __shfl_xor(sf, 1, 64);
        if (!(t & 1)) {
            size_t base = ((size_t)(ab * 32 + b) * 16 + yg) * 128 + c;
            mpart[base] = sx * (1.f / 1024.f);
            mpart[MPK + base] = sf * (1.f / 1024.f);
        }
    }
}

// ---- conv1: K-64 steps (18), T4 counted-vmcnt (2 raw barriers, no drain) ----
__global__ __launch_bounds__(256, 2) void k_conv1g(const u16* __restrict__ XC,
                                                   const u16* __restrict__ A1p,
                                                   u16* __restrict__ CC) {
    __shared__ u16 sA[2][8192];
    __shared__ u16 sB[2][4096];
    int t = threadIdx.x, l = t & 63, l15 = l & 15, lq = l >> 4, w = t >> 6;
    int wm = w & 1, wn = w >> 1;
    int Nt = blockIdx.x, b = blockIdx.y;
    int ab = blockIdx.z & 1, Mt = blockIdx.z >> 1;
    const u16* xc = XC + (size_t)ab * XSZ + (size_t)b * XBS;
    const u16* Ag = A1p + (size_t)Mt * (36 * 4096);
    int bpos0 = (8 * Nt + 2 * (l >> 4)) * 34 + 2 * (l & 15);
    const int po1[9] = {0, 1, 2, 34, 35, 36, 68, 69, 70};

    auto stageA = [&](int buf, int kcA) {
        const u16* ga = Ag + (size_t)kcA * 4096 + t * 8;
        u16* da = &sA[buf][w * 512];
#pragma unroll
        for (int i = 0; i < 4; ++i) gll16(ga + i * 2048, da + i * 2048);
    };
    auto stageB = [&](int buf, int po, int s) {
#pragma unroll
        for (int i = 0; i < 2; ++i) {
            int ks = i * 4 + w;
            gll16(xc + ((size_t)(s * 8 + ks) * 1156 + bpos0 + po) * 8,
                  &sB[buf][(size_t)ks * 512]);
        }
    };

    f4 acc[4][2] = {};
    stageA(0, 0);
    stageB(0, 0, 0);
    int cur = 0;
#pragma unroll
    for (int ti = 0; ti < 9; ++ti) {
        const int po = po1[ti];
        const int poN = (ti < 8) ? po1[ti + 1] : 0;
#pragma unroll 1
        for (int s = 0; s < 2; ++s) {
            __builtin_amdgcn_s_barrier();
            bool last = (ti == 8) && (s == 1);
            if (!last) {
                int tin = (s < 1) ? ti : ti + 1;
                int sn = (s < 1) ? 1 : 0;
                stageA(cur ^ 1, tin * 4 + sn * 2);
                stageB(cur ^ 1, (s < 1) ? po : poN, sn);
                asm volatile("s_waitcnt vmcnt(6)" ::: "memory");
            } else {
                asm volatile("s_waitcnt vmcnt(0)" ::: "memory");
            }
            __builtin_amdgcn_s_barrier();
            const u16* As = sA[cur];
            const u16* Bs = sB[cur];
#pragma unroll
            for (int kc2 = 0; kc2 < 2; ++kc2) {
                bf8 af[4], bv[2];
#pragma unroll
                for (int mf = 0; mf < 4; ++mf)
                    af[mf] = *(const bf8*)(As + ((kc2 * 4 + lq) * 128 + wm * 64 + mf * 16 + l15) * 8);
#pragma unroll
                for (int nf = 0; nf < 2; ++nf)
                    bv[nf] = *(const bf8*)(Bs + ((kc2 * 4 + lq) * 64 + wn * 32 + nf * 16 + l15) * 8);
#pragma unroll
                for (int mf = 0; mf < 4; ++mf)
#pragma unroll
                    for (int nf = 0; nf < 2; ++nf)
                        acc[mf][nf] = __builtin_amdgcn_mfma_f32_16x16x32_bf16(af[mf], bv[nf], acc[mf][nf], 0, 0, 0);
            }
            cur ^= 1;
        }
    }
    u16* cb = CC + (size_t)ab * CSZ + (size_t)b * CBS;
#pragma unroll
    for (int mf = 0; mf < 4; ++mf) {
        int mc = Mt * 128 + wm * 64 + mf * 16 + lq * 4;
#pragma unroll
        for (int nf = 0; nf < 2; ++nf) {
            int nl = wn * 32 + nf * 16 + l15;
            int oh = Nt * 4 + (nl >> 4), ow = nl & 15;
            int posO = (1 + oh) * 18 + 1 + ow;
            us4 pk;
#pragma unroll
            for (int r = 0; r < 4; ++r) pk.v[r] = f2bf(fmaxf(acc[mf][nf][r], 0.f));
            *(us4*)(cb + ((size_t)(mc >> 3) * 324 + posO) * 8 + (mc & 7)) = pk;
        }
    }
}

// ---- k_cde11: 512 balanced blocks; T4 counted-vmcnt KSTEP; bf16 conv2 partials ----
#define KSTEP(ACC, KYV, KXV, HN, KCAN)                                              \
    {                                                                               \
        __builtin_amdgcn_s_barrier();                                               \
        if (HN) {                                                                   \
            stageA(cur ^ 1, (KCAN));                                                \
            asm volatile("s_waitcnt vmcnt(4)" ::: "memory");                        \
        } else {                                                                    \
            asm volatile("s_waitcnt vmcnt(0)" ::: "memory");                        \
        }                                                                           \
        __builtin_amdgcn_s_barrier();                                               \
        const u16* As = sA[cur];                                                    \
        _Pragma("unroll") for (int kc2 = 0; kc2 < 2; ++kc2) {                       \
            _Pragma("unroll") for (int j = 0; j < 2; ++j) {                         \
                bf8 a0 = *(const bf8*)(As + kc2 * 4096 + j * 2048 + aBase);         \
                bf8 a1 = *(const bf8*)(As + kc2 * 4096 + j * 2048 + aBase + 256);   \
                const u16* bp = sS + (kc2 * 720 + j * 360) * 8 + bBase;             \
                bf8 b0 = *(const bf8*)(bp + (((KYV)) * 18 + (KXV)) * 8);            \
                bf8 b1 = *(const bf8*)(bp + (((KYV) + 2) * 18 + (KXV)) * 8);        \
                ACC[0][0] = __builtin_amdgcn_mfma_f32_32x32x16_bf16(a0, b0, ACC[0][0], 0, 0, 0); \
                ACC[0][1] = __builtin_amdgcn_mfma_f32_32x32x16_bf16(a0, b1, ACC[0][1], 0, 0, 0); \
                ACC[1][0] = __builtin_amdgcn_mfma_f32_32x32x16_bf16(a1, b0, ACC[1][0], 0, 0, 0); \
                ACC[1][1] = __builtin_amdgcn_mfma_f32_32x32x16_bf16(a1, b1, ACC[1][1], 0, 0, 0); \
            }                                                                       \
        }                                                                           \
        cur ^= 1;                                                                   \
    }

#define FLUSH(ACC, PY, PX)                                                          \
    _Pragma("unroll") for (int mf = 0; mf < 2; ++mf) {                              \
        _Pragma("unroll") for (int nf = 0; nf < 2; ++nf) {                          \
            int n = wn * 64 + nf * 32 + l31;                                        \
            int oh = 8 * Nt + (n >> 4), ow = n & 15;                                \
            int Y = 2 * oh + (PY), X = 2 * ow + (PX);                               \
            _Pragma("unroll") for (int rg = 0; rg < 4; ++rg) {                      \
                int mc = wm * 64 + mf * 32 + 8 * rg + 4 * lh;                       \
                us4 xv = *(const us4*)(xq + (size_t)(mc >> 3) * 1156 * 8 +          \
                                       (size_t)(Y * 34 + X) * 8 + (mc & 7));        \
                _Pragma("unroll") for (int r = 0; r < 4; ++r) {                     \
                    float d = ACC[mf][nf][rg * 4 + r] - bf2f(xv.v[r]);              \
                    ss = fmaf(d, d, ss);                                            \
                }                                                                   \
            }                                                                       \
        }                                                                           \
    }

__global__ __launch_bounds__(256, 2) void k_cde11(const u16* __restrict__ CC,
                                                  const u16* __restrict__ A2p,
                                                  const u16* __restrict__ A3p,
                                                  const u16* __restrict__ XC,
                                                  u16* __restrict__ pc0,
                                                  u16* __restrict__ pc1,
                                                  float* __restrict__ prpart) {
    __shared__ u16 sS[11520];     // [ccL8][pos 10x18][8e] = 22.5KB
    __shared__ u16 sA[2][8192];   // A dbuf 2x16KB
    __shared__ float lds4[4];
    int t = threadIdx.x, l = t & 63, l31 = l & 31, lh = l >> 5, w = t >> 6;
    int wm = w & 1, wn = w >> 1;
    int Nt = blockIdx.x, b = blockIdx.y;
    int ab = blockIdx.z & 1, unit = blockIdx.z >> 1;
    const u16* cbb = CC + (size_t)ab * CSZ + (size_t)b * CBS;
    const u16* xq = XC + (size_t)ab * XSZ + (size_t)b * XBS;
    const u16* Ag = (unit < 2) ? A2p : A3p;
    int r0 = 8 * Nt;
    int aBase = (lh * 128 + wm * 64 + l31) * 8;
    int bBase = (lh * 180 + (wn * 4 + (l31 >> 4)) * 18 + (l31 & 15)) * 8;

    auto stageA = [&](int buf, int kcA) {
        const u16* ga = Ag + (size_t)kcA * 4096 + t * 8;
        u16* da = &sA[buf][w * 512];
#pragma unroll
        for (int i = 0; i < 4; ++i) gll16(ga + i * 2048, da + i * 2048);
    };
    auto stage_slab = [&](int seg) {
        if (t < 180) {
            int cc0 = (seg >> 1) * 16 + (seg & 1) * 8;
#pragma unroll 1
            for (int ccL = 0; ccL < 8; ++ccL) {
                us8 v = *(const us8*)(cbb + ((size_t)(cc0 + ccL) * 324 + r0 * 18 + t) * 8);
                *(us8*)(sS + ((size_t)ccL * 180 + t) * 8) = v;
            }
        }
    };

    int cur = 0;
    float ss = 0.f;
    if (unit < 2) {
        f16v acc[2][2] = {};
        int segBase = unit * 2;
        stage_slab(segBase);
        stageA(0, (segBase >> 1) * 4 + (segBase & 1) * 2);
#pragma unroll
        for (int sl = 0; sl < 2; ++sl) {
            int seg = segBase + sl;
            if (sl) { __syncthreads(); stage_slab(seg); }
#pragma unroll 1
            for (int tap = 0; tap < 9; ++tap) {
                int s = sl * 9 + tap;
                int ky = tap / 3, kx = tap - ky * 3;
                bool hn = s < 17;
                int s1 = hn ? s + 1 : 0;
                int sl1 = s1 / 9, tap1 = s1 - sl1 * 9;
                int seg1 = segBase + sl1;
                int kcan = tap1 * 8 + (seg1 >> 1) * 4 + (seg1 & 1) * 2;
                KSTEP(acc, ky, kx, hn, kcan);
            }
        }
        u16* pw = (unit == 0 ? pc0 : pc1) + (size_t)(ab * 32 + b) * 32768;
#pragma unroll
        for (int mf = 0; mf < 2; ++mf)
#pragma unroll
            for (int nf = 0; nf < 2; ++nf) {
                int pos = 128 * Nt + wn * 64 + nf * 32 + l31;
                u16* row = pw + (size_t)pos * 128 + wm * 64 + mf * 32 + 4 * lh;
#pragma unroll
                for (int g = 0; g < 4; ++g) {
                    us4 pk;
#pragma unroll
                    for (int r = 0; r < 4; ++r) pk.v[r] = f2bf(acc[mf][nf][4 * g + r]);
                    *(us4*)(row + 8 * g) = pk;
                }
            }
    } else if (unit == 2) {
        f16v accP[2][2] = {}, accQ[2][2] = {};
        stage_slab(0);
        stageA(0, 0);
#pragma unroll
        for (int seg = 0; seg < 4; ++seg) {
            if (seg) { __syncthreads(); stage_slab(seg); }
#pragma unroll 1
            for (int r = 0; r < 5; ++r) {
                int s = seg * 5 + r;
                bool hn = s < 19;
                int s1 = hn ? s + 1 : 0;
                int seg1 = s1 / 5, r1 = s1 - seg1 * 5;
                int tapi1 = (r1 < 4) ? r1 : 8;
                int kcan = tapi1 * 8 + (seg1 >> 1) * 4 + (seg1 & 1) * 2;
                if (r < 4) {
                    int dy = r >> 1, dx = r & 1;
                    KSTEP(accP, dy, dx, hn, kcan);
                } else {
                    KSTEP(accQ, 1, 1, hn, kcan);
                }
            }
        }
        FLUSH(accP, 0, 0);
        FLUSH(accQ, 1, 1);
        ss = blockSum256(ss, lds4);
        if (t == 0) prpart[ab * 128 + Nt * 32 + b] = ss;
    } else {
        f16v accP[2][2] = {}, accQ[2][2] = {};
        stage_slab(0);
        stageA(0, 32);
#pragma unroll
        for (int seg = 0; seg < 4; ++seg) {
            if (seg) { __syncthreads(); stage_slab(seg); }
#pragma unroll 1
            for (int r = 0; r < 4; ++r) {
                int s = seg * 4 + r;
                bool hn = s < 15;
                int s1 = hn ? s + 1 : 0;
                int seg1 = s1 >> 2, r1 = s1 & 3;
                int kcan = (4 + r1) * 8 + (seg1 >> 1) * 4 + (seg1 & 1) * 2;
                if (r < 2) {
                    KSTEP(accP, r, 1, hn, kcan);
                } else {
                    KSTEP(accQ, 1, r - 2, hn, kcan);
                }
            }
        }
        FLUSH(accP, 0, 1);
        FLUSH(accQ, 1, 0);
        ss = blockSum256(ss, lds4);
        if (t == 0) prpart[ab * 128 + 64 + Nt * 32 + b] = ss;
    }
}

#undef KSTEP
#undef FLUSH

// ---- metric: 256 threads/block; conv2-reduce split across half-blocks ----
__global__ __launch_bounds__(256) void k_metric(const u16* __restrict__ pc0,
                                                const u16* __restrict__ pc1,
                                                const float* __restrict__ mpart,
                                                const float* __restrict__ PnT,
                                                const float* __restrict__ pn2,
                                                const int* __restrict__ la,
                                                const int* __restrict__ lb,
                                                float* __restrict__ mo) {
    __shared__ float lds4[4];
    __shared__ float sred[256];
    __shared__ float xs[128];
    int blk = blockIdx.x;
    int t = threadIdx.x;
    int b = blk & 31;
    int oc = t & 127, th = t >> 7;   // th = pos-half
    float xv = 0.f;
    if (blk < 64) {
        int ab = blk >> 5;
        const u16* p0 = pc0 + (size_t)(ab * 32 + b) * 32768 + (size_t)th * 128 * 128;
        const u16* p1 = pc1 + (size_t)(ab * 32 + b) * 32768 + (size_t)th * 128 * 128;
        float s = 0.f;
#pragma unroll 4
        for (int pos = 0; pos < 128; ++pos)
            s += fmaxf(bf2f(p0[pos * 128 + oc]) + bf2f(p1[pos * 128 + oc]), 0.f);
        sred[t] = s;
        __syncthreads();
        if (t < 128) xv = (sred[t] + sred[t + 128]) * (1.f / 256.f);
    } else {
        if (t < 128) {
            int abx = (blk < 96) ? 0 : 1;
            int abf = 1 - abx;
            const float* mx = mpart + ((size_t)(abx * 32 + b) * 16) * 128 + t;
            const float* mf = mpart + MPK + ((size_t)(abf * 32 + b) * 16) * 128 + t;
            float s = 0.f;
#pragma unroll
            for (int yg = 0; yg < 16; ++yg)
                s += LAMF * mx[yg * 128] + ILAMF * mf[yg * 128];
            xv = s;
        }
    }
    float ssq = blockSum256(xv * xv, lds4);
    float sc = SCALEF / fmaxf(sqrtf(ssq), 1e-12f);
    float xn = xv * sc;
    if (t < 128) xs[t] = xn;
    float xn2 = blockSum256(xn * xn, lds4);   // has syncthreads -> xs visible
    bool active = (t < NB);
    float Dk = 1e30f;
    if (active) {
        float dot = 0.f;
#pragma unroll 8
        for (int e = 0; e < CI; ++e) dot = fmaf(xs[e], PnT[e * NB + t], dot);
        Dk = xn2 + pn2[t] - 2.f * dot;
    }
    float z = active ? -Dk : -1e30f;
    float m = blockMax256(z, lds4);
    float e = active ? expf(z - m) : 0.f;
    float se = blockSum256(e, lds4);
    float lse = m + logf(se);
    if (t == 0) mo[blk * 3 + 0] = lse;
    int A = la[b], Bb = lb[b];
    if (t == A) mo[blk * 3 + 1] = Dk;
    if (t == Bb) mo[blk * 3 + 2] = Dk;
}

__global__ __launch_bounds__(128) void k_final(const float* __restrict__ prpart,
                                               const float* __restrict__ mo,
                                               float* __restrict__ out) {
    __shared__ float lds2[2];
    __shared__ float mla[4], mlb[4];
    int t = threadIdx.x;
    float sa = blockSum128(prpart[t], lds2);
    float sb = blockSum128(prpart[128 + t], lds2);
    const float* m = mo + t * 3;
    float ula = m[0] + m[1];
    float ulb = m[0] + m[2];
#pragma unroll
    for (int off = 16; off > 0; off >>= 1) {
        ula += __shfl_down(ula, off, 32);
        ulb += __shfl_down(ulb, off, 32);
    }
    if ((t & 31) == 0) { mla[t >> 5] = ula * (1.f / 32.f); mlb[t >> 5] = ulb * (1.f / 32.f); }
    __syncthreads();
    if (t == 0) {
        float lxa = sa * (1.f / 4194304.f);
        float lxb = sb * (1.f / 4194304.f);
        float lca = mla[0];
        float lcb = mlb[1];
        float lcma = LAMF * mla[2] + ILAMF * mlb[2];
        float lcmb = LAMF * mlb[3] + ILAMF * mla[3];
        out[0] = lxa + lxb + lca + lcb + lcma + lcmb;
        out[1] = lxa; out[2] = lxb; out[3] = lca; out[4] = lcb; out[5] = lcma; out[6] = lcmb;
    }
}

extern "C" void kernel_launch(void* const* d_in, const int* in_sizes, int n_in,
                              void* d_out, int out_size, void* d_ws, size_t ws_size,
                              hipStream_t stream) {
    const float* xa = (const float*)d_in[0];
    const float* xb = (const float*)d_in[1];
    const int* la = (const int*)d_in[2];
    const int* lb = (const int*)d_in[3];
    const float* P = (const float*)d_in[4];
    const float* We = (const float*)d_in[5];
    const float* Wf = (const float*)d_in[6];
    const float* Wd = (const float*)d_in[7];

    char* w = (char*)d_ws;
    const size_t XPAD_B = XSZ * 2 * sizeof(u16);
    const size_t CPAD_B = CSZ * 2 * sizeof(u16);
    const size_t AW_B = (size_t)294912 * 2;
    u16* xpad = (u16*)w;                 w += XPAD_B;
    u16* cpad = (u16*)w;                 w += CPAD_B;
    u16* A1p = (u16*)w;                  w += AW_B;
    u16* A2p = (u16*)w;                  w += AW_B;
    u16* A3p = (u16*)w;                  w += AW_B;
    float* PnT = (float*)w;              w += 12800 * 4;
    float* pn2 = (float*)w;              w += 128 * 4;
    float* mpart = (float*)w;            w += MPK * 2 * 4;
    float* prpart = (float*)w;           w += 256 * 4;
    float* mo = (float*)w;               w += 384 * 4;
    u16* pc0 = (u16*)w;                  w += (size_t)2 * 32 * 32768 * 2;  // 4.2MB
    u16* pc1 = (u16*)w;                  w += (size_t)2 * 32 * 32768 * 2;  // 4.2MB
    float* out = (float*)d_out;

    k_setup<<<2290, 256, 0, stream>>>(xa, xb, P, We, Wf, Wd, A1p, A2p, A3p,
                                      PnT, pn2, xpad, cpad, mpart);
    k_conv1g<<<dim3(4, 32, 4), 256, 0, stream>>>(xpad, A1p, cpad);
    k_cde11<<<dim3(2, 32, 8), 256, 0, stream>>>(cpad, A2p, A3p, xpad, pc0, pc1, prpart);
    k_metric<<<128, 256, 0, stream>>>(pc0, pc1, mpart, PnT, pn2, la, lb, mo);
    k_final<<<1, 128, 0, stream>>>(prpart, mo, out);
}